// Round 1
// baseline (542.575 us; speedup 1.0000x reference)
//
#include <hip/hip_runtime.h>
#include <hip/hip_bf16.h>
#include <math.h>

#define E_ 64
#define H_ 512
#define F_ 2048

typedef __bf16 bf16_t;
typedef __attribute__((ext_vector_type(8))) __bf16 bfrag_t;
typedef __attribute__((ext_vector_type(4))) float f32x4;

union U8 {
  bfrag_t v;
  unsigned u[4];
  unsigned short s[8];
};

// pack two fp32 -> two bf16 (RNE) in one u32: low16 = bf16(a), high16 = bf16(b)
__device__ __forceinline__ unsigned pk2(float a, float b) {
  unsigned ua = __float_as_uint(a), ub = __float_as_uint(b);
  ua += 0x7FFFu + ((ua >> 16) & 1u);
  ub += 0x7FFFu + ((ub >> 16) & 1u);
  return __builtin_amdgcn_perm(ub, ua, 0x07060302u);
}

__device__ __forceinline__ unsigned short bf1(float a) {
  unsigned ua = __float_as_uint(a);
  ua += 0x7FFFu + ((ua >> 16) & 1u);
  return (unsigned short)(ua >> 16);
}

__device__ __forceinline__ void get_off(const int* cnts, int e, int tid, int* sh,
                                        int& offs, int& cnt) {
  if (tid == 0) {
    int o = 0;
    for (int i = 0; i < e; ++i) o += cnts[i];
    sh[0] = o;
    sh[1] = cnts[e];
  }
  __syncthreads();
  offs = sh[0];
  cnt = sh[1];
}

// ---------------- Kernel 1: h = gelu(x @ w1^T), h stored bf16 [T][F] ----------------
// grid (F/256, E), block 256. Wave covers 64 f (4 n-tiles of 16). Token chunk = 48.
// B (w1) stream prefetched DEPTH 2 (a*/b* ping-pong): loads for k+64 issued while k
// computes -> 16 dwordx4 in flight per wave instead of 8.
#define XS_STRIDE 520  // 512 + 8 pad (keeps 16B alignment for b128 A-frag reads)
#define CH1 48

__global__ __launch_bounds__(256, 2) void k1_gemm(const float* __restrict__ x,
                                                  const float* __restrict__ w1,
                                                  const int* __restrict__ cnts,
                                                  bf16_t* __restrict__ hws) {
  __shared__ unsigned short xs[CH1 * XS_STRIDE];
  __shared__ int sh[2];
  const int tid = threadIdx.x;
  const int e = blockIdx.y;
  const int fblk = blockIdx.x * 256;
  int offs, cnt;
  get_off(cnts, e, tid, sh, offs, cnt);
  if (cnt <= 0) return;

  const float* w1e = w1 + (size_t)e * F_ * H_;
  const int wv = tid >> 6, lane = tid & 63, ln = lane & 15, q = lane >> 4;

  const float* bp[4];
#pragma unroll
  for (int nt = 0; nt < 4; ++nt)
    bp[nt] = w1e + (size_t)(fblk + wv * 64 + nt * 16 + ln) * H_ + q * 8;

  for (int tok0 = 0; tok0 < cnt; tok0 += CH1) {
    const int ncur = min(cnt - tok0, CH1);
    __syncthreads();
    // stage x chunk -> LDS bf16
    const int total4 = ncur * (H_ / 4);
    for (int i = tid; i < total4; i += 256) {
      const int row = i >> 7, c4 = i & 127;
      const float4 v = ((const float4*)(x + (size_t)(offs + tok0 + row) * H_))[c4];
      unsigned* dst = (unsigned*)&xs[row * XS_STRIDE + c4 * 4];
      dst[0] = pk2(v.x, v.y);
      dst[1] = pk2(v.z, v.w);
    }
    __syncthreads();

    f32x4 acc[3][4];
#pragma unroll
    for (int mt = 0; mt < 3; ++mt)
#pragma unroll
      for (int nt = 0; nt < 4; ++nt) acc[mt][nt] = (f32x4)(0.0f);

    // depth-2 prefetch: a* holds even k-step (k0), b* holds odd (k0+32)
    float4 a0[4], a1[4], b0[4], b1[4];
#pragma unroll
    for (int nt = 0; nt < 4; ++nt) {
      a0[nt] = *(const float4*)(bp[nt]);
      a1[nt] = *(const float4*)(bp[nt] + 4);
      b0[nt] = *(const float4*)(bp[nt] + 32);
      b1[nt] = *(const float4*)(bp[nt] + 36);
    }

    for (int k0 = 0; k0 < H_; k0 += 64) {
      // -------- substep A: k = k0, consumes a*, prefetches k0+64 --------
      {
        U8 bfv[4];
#pragma unroll
        for (int nt = 0; nt < 4; ++nt) {
          bfv[nt].u[0] = pk2(a0[nt].x, a0[nt].y);
          bfv[nt].u[1] = pk2(a0[nt].z, a0[nt].w);
          bfv[nt].u[2] = pk2(a1[nt].x, a1[nt].y);
          bfv[nt].u[3] = pk2(a1[nt].z, a1[nt].w);
        }
        if (k0 + 64 < H_) {
#pragma unroll
          for (int nt = 0; nt < 4; ++nt) {
            a0[nt] = *(const float4*)(bp[nt] + k0 + 64);
            a1[nt] = *(const float4*)(bp[nt] + k0 + 68);
          }
        }
#pragma unroll
        for (int mt = 0; mt < 3; ++mt) {
          if (mt * 16 < ncur) {
            U8 af;
            af.v = *(const bfrag_t*)(xs + (mt * 16 + ln) * XS_STRIDE + k0 + q * 8);
#pragma unroll
            for (int nt = 0; nt < 4; ++nt)
              acc[mt][nt] =
                  __builtin_amdgcn_mfma_f32_16x16x32_bf16(af.v, bfv[nt].v, acc[mt][nt], 0, 0, 0);
          }
        }
      }
      // -------- substep B: k = k0+32, consumes b*, prefetches k0+96 --------
      {
        U8 bfv[4];
#pragma unroll
        for (int nt = 0; nt < 4; ++nt) {
          bfv[nt].u[0] = pk2(b0[nt].x, b0[nt].y);
          bfv[nt].u[1] = pk2(b0[nt].z, b0[nt].w);
          bfv[nt].u[2] = pk2(b1[nt].x, b1[nt].y);
          bfv[nt].u[3] = pk2(b1[nt].z, b1[nt].w);
        }
        if (k0 + 96 < H_) {
#pragma unroll
          for (int nt = 0; nt < 4; ++nt) {
            b0[nt] = *(const float4*)(bp[nt] + k0 + 96);
            b1[nt] = *(const float4*)(bp[nt] + k0 + 100);
          }
        }
#pragma unroll
        for (int mt = 0; mt < 3; ++mt) {
          if (mt * 16 < ncur) {
            U8 af;
            af.v = *(const bfrag_t*)(xs + (mt * 16 + ln) * XS_STRIDE + (k0 + 32) + q * 8);
#pragma unroll
            for (int nt = 0; nt < 4; ++nt)
              acc[mt][nt] =
                  __builtin_amdgcn_mfma_f32_16x16x32_bf16(af.v, bfv[nt].v, acc[mt][nt], 0, 0, 0);
          }
        }
      }
    }

    // epilogue: gelu(exact) -> bf16 store. D layout: col = lane&15, row = q*4 + r
#pragma unroll
    for (int mt = 0; mt < 3; ++mt) {
      if (mt * 16 < ncur) {
#pragma unroll
        for (int r = 0; r < 4; ++r) {
          const int tl = mt * 16 + q * 4 + r;
          if (tl < ncur) {
            const size_t rowbase = (size_t)(offs + tok0 + tl) * F_;
#pragma unroll
            for (int nt = 0; nt < 4; ++nt) {
              const float vv = acc[mt][nt][r];
              const float g = 0.5f * vv * (1.0f + erff(vv * 0.70710678118654752440f));
              hws[rowbase + fblk + wv * 64 + nt * 16 + ln] = (bf16_t)g;
            }
          }
        }
      }
    }
  }
}

// ---------------- Kernel 2: out = h @ w2, out fp32 [T][H] ----------------
// grid (H/64, E), block 256. Wave owns one 16-col n-tile. w2 tile transposed via LDS
// (double-buffered). h A-frags now prefetched ONE ks-step AHEAD (afA/afB ping-pong)
// so MFMAs never wait on same-iteration global loads.
#define W2S 66  // lds row stride (elems): keeps 4B alignment for b32 frag reads

// One ks step: consumes AFU, prefetches AFP for ks+1, stages w2 for ks+1.
#define K2_STEP(ks, AFU, AFP)                                                              \
  {                                                                                        \
    __syncthreads(); /* bs[(ks)&1] writes done */                                          \
    if ((ks) + 1 < NK) {                                                                   \
      _Pragma("unroll") for (int i = 0; i < 4; ++i) pv[i] =                                \
          *(const float4*)(w2e + (size_t)(((ks) + 1) * 64 + rid + 16 * i) * H_ + c0 +      \
                           cid * 4);                                                       \
      _Pragma("unroll") for (int mt = 0; mt < 4; ++mt) {                                   \
        if (mt * 16 < ncur) {                                                              \
          const size_t rb = (size_t)(offs + tok0 + min(mt * 16 + ln, ncur - 1)) * F_;      \
          _Pragma("unroll") for (int ki = 0; ki < 2; ++ki) AFP[mt][ki].v =                 \
              *(const bfrag_t*)(hws + rb + ((ks) + 1) * 64 + ki * 32 + q * 8);             \
        }                                                                                  \
      }                                                                                    \
    }                                                                                      \
    const unsigned short* buf = bs[(ks) & 1];                                              \
    _Pragma("unroll") for (int ki = 0; ki < 2; ++ki) {                                     \
      U8 bfv;                                                                              \
      const unsigned* bp32 = (const unsigned*)(buf + (wv * 16 + ln) * W2S + ki * 32 +      \
                                               q * 8);                                     \
      bfv.u[0] = bp32[0];                                                                  \
      bfv.u[1] = bp32[1];                                                                  \
      bfv.u[2] = bp32[2];                                                                  \
      bfv.u[3] = bp32[3];                                                                  \
      _Pragma("unroll") for (int mt = 0; mt < 4; ++mt) {                                   \
        if (mt * 16 < ncur)                                                                \
          acc[mt] = __builtin_amdgcn_mfma_f32_16x16x32_bf16(AFU[mt][ki].v, bfv.v, acc[mt], \
                                                            0, 0, 0);                      \
      }                                                                                    \
    }                                                                                      \
    if ((ks) + 1 < NK) {                                                                   \
      _Pragma("unroll") for (int i = 0; i < 4; ++i) {                                      \
        const int fl = rid + 16 * i;                                                       \
        const float* pf = (const float*)&pv[i];                                            \
        _Pragma("unroll") for (int j = 0; j < 4; ++j)                                      \
            bs[((ks) + 1) & 1][(cid * 4 + j) * W2S + fl] = bf1(pf[j]);                     \
      }                                                                                    \
    }                                                                                      \
  }

__global__ __launch_bounds__(256, 2) void k2_gemm(const bf16_t* __restrict__ hws,
                                                  const float* __restrict__ w2,
                                                  const int* __restrict__ cnts,
                                                  float* __restrict__ out) {
  __shared__ unsigned short bs[2][64 * W2S];
  __shared__ int sh[2];
  const int tid = threadIdx.x;
  const int e = blockIdx.y;
  const int c0 = blockIdx.x * 64;
  int offs, cnt;
  get_off(cnts, e, tid, sh, offs, cnt);
  if (cnt <= 0) return;

  const float* w2e = w2 + (size_t)e * F_ * H_;
  const int wv = tid >> 6, lane = tid & 63, ln = lane & 15, q = lane >> 4;
  const int rid = tid >> 4, cid = tid & 15;  // staging: rows f = rid+16i, cols c = cid*4..+3
  const int NK = F_ / 64;                    // 32 k-steps of 64

  for (int tok0 = 0; tok0 < cnt; tok0 += 64) {
    const int ncur = min(cnt - tok0, 64);
    f32x4 acc[4];
#pragma unroll
    for (int mt = 0; mt < 4; ++mt) acc[mt] = (f32x4)(0.0f);

    float4 pv[4];
    // stage w2 tile for ks=0 into bs[0]
#pragma unroll
    for (int i = 0; i < 4; ++i)
      pv[i] = *(const float4*)(w2e + (size_t)(rid + 16 * i) * H_ + c0 + cid * 4);
#pragma unroll
    for (int i = 0; i < 4; ++i) {
      const int fl = rid + 16 * i;
      const float* pf = (const float*)&pv[i];
#pragma unroll
      for (int j = 0; j < 4; ++j) bs[0][(cid * 4 + j) * W2S + fl] = bf1(pf[j]);
    }

    // preload A-frags for ks=0
    U8 afA[4][2], afB[4][2];
#pragma unroll
    for (int mt = 0; mt < 4; ++mt) {
      if (mt * 16 < ncur) {
        const size_t rb = (size_t)(offs + tok0 + min(mt * 16 + ln, ncur - 1)) * F_;
#pragma unroll
        for (int ki = 0; ki < 2; ++ki)
          afA[mt][ki].v = *(const bfrag_t*)(hws + rb + ki * 32 + q * 8);
      }
    }

    for (int ks2 = 0; ks2 < NK; ks2 += 2) {
      K2_STEP(ks2, afA, afB);
      K2_STEP(ks2 + 1, afB, afA);
    }

    // epilogue
#pragma unroll
    for (int mt = 0; mt < 4; ++mt) {
      if (mt * 16 < ncur) {
#pragma unroll
        for (int r = 0; r < 4; ++r) {
          const int tl = mt * 16 + q * 4 + r;
          if (tl < ncur)
            out[(size_t)(offs + tok0 + tl) * H_ + c0 + wv * 16 + ln] = acc[mt][r];
        }
      }
    }
    __syncthreads();  // protect bs before next chunk restages
  }
}

extern "C" void kernel_launch(void* const* d_in, const int* in_sizes, int n_in, void* d_out,
                              int out_size, void* d_ws, size_t ws_size, hipStream_t stream) {
  const float* x = (const float*)d_in[0];
  const float* w1 = (const float*)d_in[1];
  const float* w2 = (const float*)d_in[2];
  const int* cnts = (const int*)d_in[3];
  float* out = (float*)d_out;
  bf16_t* hws = (bf16_t*)d_ws;  // T*F bf16 = 8 MB

  k1_gemm<<<dim3(F_ / 256, E_), 256, 0, stream>>>(x, w1, cnts, hws);
  k2_gemm<<<dim3(H_ / 64, E_), 256, 0, stream>>>(hws, w2, cnts, out);
}